// Round 10
// baseline (436.116 us; speedup 1.0000x reference)
//
#include <hip/hip_runtime.h>
#include <cstddef>
#include <cstdint>

typedef _Float16 half8 __attribute__((ext_vector_type(8)));
typedef float floatx4 __attribute__((ext_vector_type(4)));
typedef float floatx16 __attribute__((ext_vector_type(16)));

static inline int cdiv_i(int a, int b) { return (a + b - 1) / b; }

// ---- fused rulebook inversion, TRANSPOSED tables: tbl[k*nout + o] = in
struct RB { const int* rin; const int* rout; int K, R, nout, start, end, off; };
struct RBs { RB d[8]; };
__global__ void rb_fill_all(RBs P, int* __restrict__ tbl, int total) {
  int idx = blockIdx.x * blockDim.x + threadIdx.x;
  if (idx >= total) return;
#pragma unroll
  for (int l = 0; l < 8; ++l) {
    if (idx >= P.d[l].start && idx < P.d[l].end) {
      const RB rb = P.d[l];
      int e = idx - rb.start;
      int o = rb.rout[e];
      if ((unsigned)o < (unsigned)rb.nout) {
        int k = e / rb.R;
        tbl[rb.off + (size_t)k * rb.nout + o] = rb.rin[e];
      }
    }
  }
}

__global__ void tbl_fill_kernel(const int* __restrict__ rin,
                                const int* __restrict__ rout,
                                int* __restrict__ tbl, int K, int R, int nout) {
  int e = blockIdx.x * blockDim.x + threadIdx.x;
  if (e >= K * R) return;
  int o = rout[e];
  if ((unsigned)o >= (unsigned)nout) return;
  int k = e / R;
  tbl[(size_t)k * nout + o] = rin[e];
}

// ---- fused prep: feat (f16 pad8) + weight pack + zero d_out, one dispatch
struct WP { const float* W; int K, Ci, CiPad, Co, start, end, off, p32; };
struct WPs {
  WP d[12];
  const float* vox; const int* vnp; _Float16* f0; int featTot, N0;
  float* dout; int outTot, wStart, wEnd;
};
__global__ void prep_all(WPs P, _Float16* __restrict__ Bp, int total) {
  int idx = blockIdx.x * blockDim.x + threadIdx.x;
  if (idx >= total) return;
  if (idx < P.featTot) {
    int i = idx >> 3, c = idx & 7;
    float v = 0.f;
    if (i < P.N0 && c < 4) {
      const float* p = P.vox + (size_t)i * 20 + c;
      v = (p[0] + p[4] + p[8] + p[12] + p[16]) / fmaxf((float)P.vnp[i], 1.f);
    }
    P.f0[idx] = (_Float16)v;
    return;
  }
  if (idx < P.featTot + P.outTot) {
    P.dout[idx - P.featTot] = 0.f;
    return;
  }
  int widx = idx - P.featTot - P.outTot;
#pragma unroll
  for (int l = 0; l < 12; ++l) {
    if (widx >= P.d[l].start && widx < P.d[l].end) {
      const WP w = P.d[l];
      int e = widx - w.start;
      int j = e & 7;
      int lane = (e >> 3) & 63;
      int rest = e >> 9;
      float v;
      if (w.p32) {
        int NT = w.Co >> 5;
        int t = rest % NT, ch = rest / NT;
        int SUB = w.CiPad >> 4;
        int ko = ch / SUB, s = ch % SUB;
        int ci = s * 16 + ((lane >> 5) << 3) + j;
        int col = t * 32 + (lane & 31);
        v = w.W[((size_t)ko * w.Ci + ci) * w.Co + col];
      } else {
        int NT = w.Co >> 4;
        int t = rest % NT, ch = rest / NT;
        int kk = ch * 32 + ((lane >> 4) << 3) + j;
        int k = kk / w.CiPad, ci = kk % w.CiPad;
        int n = t * 16 + (lane & 15);
        v = (k < w.K && ci < w.Ci) ? w.W[((size_t)k * w.Ci + ci) * w.Co + n] : 0.f;
      }
      Bp[w.off + e] = (_Float16)v;
    }
  }
}

// ======== 16x16x32 path (narrow layers + conv_out) ========
// CONTIGUOUS-k per wave: wave ks owns chunks [ks*NCW, (ks+1)*NCW)
template <int K, int CiPad, int Co, int KS, int CG, int CBLK>
__global__ __launch_bounds__(256) void conv_mfma(
    const _Float16* __restrict__ feat, const _Float16* __restrict__ Bp,
    const int* __restrict__ tbl, const float* __restrict__ sc,
    const float* __restrict__ bi, _Float16* __restrict__ out,
    int nout, int nin) {
  constexpr int NT = Co / 16;
  constexpr int NTE = NT / CBLK;
  constexpr int NTW = NTE / CG;
  constexpr int RG = 4 / (KS * CG);
  static_assert(KS * CG * RG == 4 && RG >= 1 && NT % CBLK == 0 && NTE % CG == 0);
  constexpr int NCH = (K * CiPad + 31) / 32;
  constexpr int L2C = (CiPad == 8) ? 3 : 4;
  constexpr int DIV = (CiPad >= 32) ? (CiPad / 32) : 1;
  constexpr int CoP = NTE * 16 + 4;

  __shared__ float red[(KS > 1) ? (KS - 1) * RG * 16 * CoP : 1];

  if (blockIdx.x == 0 && threadIdx.x < Co)
    out[(size_t)nout * Co + threadIdx.x] = (_Float16)0.f;

  int id = blockIdx.x;
  { int nb = gridDim.x, nb8 = (nb >> 3) << 3;
    if (id < nb8) { int per = nb >> 3; id = (id & 7) * per + (id >> 3); } }
  const int rt = id / CBLK, cb = id % CBLK;
  const int wave = threadIdx.x >> 6, lane = threadIdx.x & 63;
  const int ks = wave % KS;
  const int cg = (wave / KS) % CG;
  const int rowg = wave / (KS * CG);
  const int m = lane & 15, lb = (lane >> 4) * 8;
  const int i0 = (rt * RG + rowg) * 16;
  if constexpr (KS == 1) { if (i0 >= nout) return; }
  const int row = i0 + m;
  const bool rOK = row < nout;
  const int ct0 = cb * NTE + cg * NTW;

  floatx4 acc[NTW];
#pragma unroll
  for (int n = 0; n < NTW; ++n) { floatx4 z = {0,0,0,0}; acc[n] = z; }

  if constexpr (CiPad >= 32) {
    constexpr int NKW = (K + KS - 1) / KS;
    constexpr int NC = NKW * DIV;
    constexpr int DA = NC < 8 ? NC : 8;
    constexpr int DB = NC < 2 ? NC : 2;
    int idx[NKW];
#pragma unroll
    for (int q = 0; q < NKW; ++q) {
      int k = ks * NKW + q;                       // contiguous k
      int jj = (rOK && k < K) ? tbl[(size_t)k * nout + row] : -1;
      idx[q] = (jj < 0) ? nin : jj;
    }
    half8 ap[DA]; half8 bq[DB][NTW];
#pragma unroll
    for (int d = 0; d < DA; ++d)
      ap[d] = *(const half8*)(feat + (size_t)idx[d / DIV] * CiPad + (d % DIV) * 32 + lb);
#pragma unroll
    for (int d = 0; d < DB; ++d) {
      int k = ks * NKW + d / DIV;
      int ch = ((k < K) ? k : (K - 1)) * DIV + (d % DIV);
#pragma unroll
      for (int n = 0; n < NTW; ++n)
        bq[d][n] = *(const half8*)(Bp + ((size_t)ch * NT * 64 + lane) * 8 +
                                   (size_t)(ct0 + n) * 512);
    }
#pragma unroll
    for (int ii = 0; ii < NC; ++ii) {
      half8 a = ap[ii % DA];
      half8 bt[NTW];
#pragma unroll
      for (int n = 0; n < NTW; ++n) bt[n] = bq[ii % DB][n];
      if (ii + DA < NC) {
        int nx = ii + DA;
        ap[ii % DA] = *(const half8*)(feat + (size_t)idx[nx / DIV] * CiPad +
                                      (nx % DIV) * 32 + lb);
      }
      if (ii + DB < NC) {
        int nx = ii + DB;
        int k = ks * NKW + nx / DIV;
        int ch = ((k < K) ? k : (K - 1)) * DIV + (nx % DIV);
#pragma unroll
        for (int n = 0; n < NTW; ++n)
          bq[ii % DB][n] = *(const half8*)(Bp + ((size_t)ch * NT * 64 + lane) * 8 +
                                           (size_t)(ct0 + n) * 512);
      }
#pragma unroll
      for (int n = 0; n < NTW; ++n)
        acc[n] = __builtin_amdgcn_mfma_f32_16x16x32_f16(a, bt[n], acc[n], 0, 0, 0);
    }
  } else {
    constexpr int NCW = (NCH + KS - 1) / KS;
    constexpr int DA = NCW < 8 ? NCW : 8;
    constexpr int DB = NCW < 2 ? NCW : 2;
    int idx[NCW];
#pragma unroll
    for (int q = 0; q < NCW; ++q) {
      int ch = ks * NCW + q;                      // contiguous chunks
      int ko = (ch * 32 + lb) >> L2C;
      int jj = (rOK && ko < K && ch < NCH) ? tbl[(size_t)ko * nout + row] : -1;
      idx[q] = (jj < 0) ? nin : jj;
    }
    half8 ap[DA]; half8 bq[DB][NTW];
#pragma unroll
    for (int d = 0; d < DA; ++d) {
      int ch = ks * NCW + d;
      ap[d] = *(const half8*)(feat + (size_t)idx[d] * CiPad + ((ch * 32 + lb) & (CiPad - 1)));
    }
#pragma unroll
    for (int d = 0; d < DB; ++d) {
      int ch = ks * NCW + d;
      if (ch >= NCH) ch = NCH - 1;
#pragma unroll
      for (int n = 0; n < NTW; ++n)
        bq[d][n] = *(const half8*)(Bp + ((size_t)ch * NT * 64 + lane) * 8 +
                                   (size_t)(ct0 + n) * 512);
    }
#pragma unroll
    for (int ii = 0; ii < NCW; ++ii) {
      half8 a = ap[ii % DA];
      half8 bt[NTW];
#pragma unroll
      for (int n = 0; n < NTW; ++n) bt[n] = bq[ii % DB][n];
      if (ii + DA < NCW) {
        int nx = ii + DA;
        int ch = ks * NCW + nx;
        ap[ii % DA] = *(const half8*)(feat + (size_t)idx[nx] * CiPad +
                                      ((ch * 32 + lb) & (CiPad - 1)));
      }
      if (ii + DB < NCW) {
        int nx = ii + DB;
        int ch = ks * NCW + nx;
        if (ch >= NCH) ch = NCH - 1;
#pragma unroll
        for (int n = 0; n < NTW; ++n)
          bq[ii % DB][n] = *(const half8*)(Bp + ((size_t)ch * NT * 64 + lane) * 8 +
                                           (size_t)(ct0 + n) * 512);
      }
#pragma unroll
      for (int n = 0; n < NTW; ++n)
        acc[n] = __builtin_amdgcn_mfma_f32_16x16x32_f16(a, bt[n], acc[n], 0, 0, 0);
    }
  }

  const int rl = (lane >> 4) * 4;
  if constexpr (KS > 1) {
    if (ks > 0) {
#pragma unroll
      for (int n = 0; n < NTW; ++n) {
        int lcol = (cg * NTW + n) * 16 + m;
#pragma unroll
        for (int r = 0; r < 4; ++r)
          red[((ks - 1) * RG + rowg) * 16 * CoP + (rl + r) * CoP + lcol] = acc[n][r];
      }
    }
    __syncthreads();
    if (ks > 0) return;
#pragma unroll
    for (int s = 1; s < KS; ++s)
#pragma unroll
      for (int n = 0; n < NTW; ++n) {
        int lcol = (cg * NTW + n) * 16 + m;
#pragma unroll
        for (int r = 0; r < 4; ++r)
          acc[n][r] += red[((s - 1) * RG + rowg) * 16 * CoP + (rl + r) * CoP + lcol];
      }
  }

#pragma unroll
  for (int n = 0; n < NTW; ++n) {
    int col = (ct0 + n) * 16 + m;
    float s_ = sc[col], b_ = bi[col];
#pragma unroll
    for (int r = 0; r < 4; ++r) {
      int orow = i0 + rl + r;
      if (orow < nout)
        out[(size_t)orow * Co + col] = (_Float16)fmaxf(fmaf(acc[n][r], s_, b_), 0.f);
    }
  }
}

// ======== 32x32x16 path (Ci>=32 layers), contiguous-k per wave ========
template <int K, int CiPad, int Co, int KS, int CG, int CBLK>
__global__ __launch_bounds__(256) void conv_mfma32(
    const _Float16* __restrict__ feat, const _Float16* __restrict__ Bp,
    const int* __restrict__ tbl, const float* __restrict__ sc,
    const float* __restrict__ bi, _Float16* __restrict__ out,
    int nout, int nin) {
  constexpr int NT = Co / 32;
  constexpr int NTE = NT / CBLK;
  constexpr int NTW = NTE / CG;
  constexpr int RG = 4 / (KS * CG);
  static_assert(KS * CG * RG == 4 && RG >= 1 && NT % CBLK == 0 && NTE % CG == 0 && NTW >= 1);
  constexpr int SUB = CiPad / 16;
  constexpr int NKW = (K + KS - 1) / KS;
  constexpr int NC = NKW * SUB;
  constexpr int DA = NC < 8 ? NC : 8;
  constexpr int DB = NC < 2 ? NC : 2;
  constexpr int CoP = NTE * 32 + 4;

  __shared__ float red[(KS > 1) ? (KS - 1) * RG * 32 * CoP : 1];

  if (blockIdx.x == 0 && threadIdx.x < Co)
    out[(size_t)nout * Co + threadIdx.x] = (_Float16)0.f;

  int id = blockIdx.x;
  { int nb = gridDim.x, nb8 = (nb >> 3) << 3;
    if (id < nb8) { int per = nb >> 3; id = (id & 7) * per + (id >> 3); } }
  const int rt = id / CBLK, cb = id % CBLK;
  const int wave = threadIdx.x >> 6, lane = threadIdx.x & 63;
  const int ks = wave % KS;
  const int cg = (wave / KS) % CG;
  const int rowg = wave / (KS * CG);
  const int m = lane & 31, lb = (lane >> 5) * 8, h = lane >> 5;
  const int i0 = (rt * RG + rowg) * 32;
  if constexpr (KS == 1) { if (i0 >= nout) return; }
  const int row = i0 + m;
  const bool rOK = row < nout;
  const int ct0 = cb * NTE + cg * NTW;

  floatx16 acc[NTW];
#pragma unroll
  for (int n = 0; n < NTW; ++n)
#pragma unroll
    for (int r = 0; r < 16; ++r) acc[n][r] = 0.f;

  int idx[NKW];
#pragma unroll
  for (int q = 0; q < NKW; ++q) {
    int k = ks * NKW + q;                         // contiguous k
    int jj = (rOK && k < K) ? tbl[(size_t)k * nout + row] : -1;
    idx[q] = (jj < 0) ? nin : jj;
  }

  half8 ap[DA]; half8 bq[DB][NTW];
#pragma unroll
  for (int d = 0; d < DA; ++d)
    ap[d] = *(const half8*)(feat + (size_t)idx[d / SUB] * CiPad + (d % SUB) * 16 + lb);
#pragma unroll
  for (int d = 0; d < DB; ++d) {
    int k = ks * NKW + d / SUB;
    int ch = ((k < K) ? k : (K - 1)) * SUB + (d % SUB);
#pragma unroll
    for (int n = 0; n < NTW; ++n)
      bq[d][n] = *(const half8*)(Bp + (size_t)(ch * NT + ct0 + n) * 512 + lane * 8);
  }
#pragma unroll
  for (int ii = 0; ii < NC; ++ii) {
    half8 a = ap[ii % DA];
    half8 bt[NTW];
#pragma unroll
    for (int n = 0; n < NTW; ++n) bt[n] = bq[ii % DB][n];
    if (ii + DA < NC) {
      int nx = ii + DA;
      ap[ii % DA] = *(const half8*)(feat + (size_t)idx[nx / SUB] * CiPad +
                                    (nx % SUB) * 16 + lb);
    }
    if (ii + DB < NC) {
      int nx = ii + DB;
      int k = ks * NKW + nx / SUB;
      int ch = ((k < K) ? k : (K - 1)) * SUB + (nx % SUB);
#pragma unroll
      for (int n = 0; n < NTW; ++n)
        bq[ii % DB][n] = *(const half8*)(Bp + (size_t)(ch * NT + ct0 + n) * 512 + lane * 8);
    }
#pragma unroll
    for (int n = 0; n < NTW; ++n)
      acc[n] = __builtin_amdgcn_mfma_f32_32x32x16_f16(a, bt[n], acc[n], 0, 0, 0);
  }

  if constexpr (KS > 1) {
    if (ks > 0) {
#pragma unroll
      for (int n = 0; n < NTW; ++n) {
        int lcol = (cg * NTW + n) * 32 + m;
#pragma unroll
        for (int reg = 0; reg < 16; ++reg) {
          int r = (reg & 3) + 8 * (reg >> 2) + 4 * h;
          red[((ks - 1) * RG + rowg) * 32 * CoP + r * CoP + lcol] = acc[n][reg];
        }
      }
    }
    __syncthreads();
    if (ks > 0) return;
#pragma unroll
    for (int s = 1; s < KS; ++s)
#pragma unroll
      for (int n = 0; n < NTW; ++n) {
        int lcol = (cg * NTW + n) * 32 + m;
#pragma unroll
        for (int reg = 0; reg < 16; ++reg) {
          int r = (reg & 3) + 8 * (reg >> 2) + 4 * h;
          acc[n][reg] += red[((s - 1) * RG + rowg) * 32 * CoP + r * CoP + lcol];
        }
      }
  }

#pragma unroll
  for (int n = 0; n < NTW; ++n) {
    int col = (ct0 + n) * 32 + m;
    float s_ = sc[col], b_ = bi[col];
#pragma unroll
    for (int reg = 0; reg < 16; ++reg) {
      int orow = i0 + (reg & 3) + 8 * (reg >> 2) + 4 * h;
      if (orow < nout)
        out[(size_t)orow * Co + col] = (_Float16)fmaxf(fmaf(acc[n][reg], s_, b_), 0.f);
    }
  }
}

// ---- two-stage segment max; batch_out nondecreasing; one atomic per run.
__global__ __launch_bounds__(256) void segmax2(const _Float16* __restrict__ x,
                                               const int* __restrict__ batch,
                                               int n, float* __restrict__ out) {
  const int RPB = 128;
  int c = threadIdx.x & 127, g = threadIdx.x >> 7;
  int r0 = blockIdx.x * RPB + g;
  int rend = min(n, blockIdx.x * RPB + RPB);
  float mx = 0.f;
  int cb = -1;
  for (int r = r0; r < rend; r += 2) {
    int b = batch[r];
    if (b != cb) {
      if (cb >= 0) atomicMax((int*)out + ((size_t)cb << 7) + c, __float_as_int(mx));
      cb = b; mx = 0.f;
    }
    mx = fmaxf(mx, (float)x[(size_t)r * 128 + c]);
  }
  if (cb >= 0) atomicMax((int*)out + ((size_t)cb << 7) + c, __float_as_int(mx));
}

extern "C" void kernel_launch(void* const* d_in, const int* in_sizes, int n_in,
                              void* d_out, int out_size, void* d_ws, size_t ws_size,
                              hipStream_t stream) {
  auto I = [&](int idx) { return (const int*)d_in[idx]; };
  auto F = [&](int idx) { return (const float*)d_in[idx]; };

  const int N0  = in_sizes[1];
  const int R1  = in_sizes[3] / 27;
  const int R2s = in_sizes[5] / 27;
  const int n2  = in_sizes[7];
  const int R2  = in_sizes[8] / 27;
  const int R3s = in_sizes[10] / 27;
  const int n3  = in_sizes[12];
  const int R3  = in_sizes[13] / 27;
  const int R4s = in_sizes[15] / 27;
  const int n4  = in_sizes[17];
  const int R4  = in_sizes[18] / 27;
  const int Ro  = in_sizes[20] / 3;
  const int no  = in_sizes[22];

  const int wIdx[12] = {23, 26, 29, 32, 35, 38, 41, 44, 47, 50, 53, 56};
  const int Ks[12]   = {27, 27, 27, 27, 27, 27, 27, 27, 27, 27, 27, 3};
  const int Cis[12]  = {4, 16, 16, 32, 32, 32, 64, 64, 64, 64, 64, 64};
  const int Cos[12]  = {16, 16, 32, 32, 32, 64, 64, 64, 64, 64, 64, 128};
  const int P32[12]  = {0, 0, 0, 1, 1, 1, 1, 1, 1, 1, 1, 0};
  WPs P;
  int wtot = 0;
  int bpOff[12];
  for (int l = 0; l < 12; ++l) {
    int cip = Cis[l] < 8 ? 8 : Cis[l];
    int sz;
    if (P32[l]) sz = Ks[l] * (cip / 16) * (Cos[l] / 32) * 512;
    else        sz = ((Ks[l] * cip + 31) / 32) * (Cos[l] / 16) * 512;
    P.d[l].W = F(wIdx[l]);
    P.d[l].K = Ks[l]; P.d[l].Ci = Cis[l]; P.d[l].CiPad = cip; P.d[l].Co = Cos[l];
    P.d[l].start = wtot; P.d[l].end = wtot + sz; P.d[l].off = wtot; P.d[l].p32 = P32[l];
    bpOff[l] = wtot;
    wtot += sz;
  }

  RBs RP;
  const int rbRin[8]  = {3, 5, 8, 10, 13, 15, 18, 20};
  const int rbRs[8]   = {R1, R2s, R2, R3s, R3, R4s, R4, Ro};
  const int rbKs[8]   = {27, 27, 27, 27, 27, 27, 27, 3};
  const int rbNout[8] = {N0, n2, n2, n3, n3, n4, n4, no};
  size_t tblInts[8], tblOff[8];
  size_t totTbl = 0;
  int totFill = 0;
  for (int l = 0; l < 8; ++l) {
    tblInts[l] = (size_t)rbNout[l] * rbKs[l];
    tblOff[l] = totTbl;
    totTbl += tblInts[l];
    RP.d[l].rin = I(rbRin[l]);
    RP.d[l].rout = I(rbRin[l] + 1);
    RP.d[l].K = rbKs[l]; RP.d[l].R = rbRs[l]; RP.d[l].nout = rbNout[l];
    RP.d[l].start = totFill;
    totFill += rbKs[l] * rbRs[l];
    RP.d[l].end = totFill;
    RP.d[l].off = (int)tblOff[l];
  }

  size_t S = (size_t)(N0 + 1) * 16;
  auto smax = [&](size_t v) { if (v > S) S = v; };
  smax((size_t)(n2 + 1) * 32);
  smax((size_t)(n3 + 1) * 64);
  smax((size_t)(n4 + 1) * 64);
  smax((size_t)(no + 1) * 128);
  S = (S + 7) & ~(size_t)7;

  _Float16* h = (_Float16*)d_ws;
  size_t off = 0;
  _Float16* f0 = h + off;   off += (size_t)(N0 + 1) * 8;
  _Float16* bufA = h + off; off += S;
  _Float16* bufB = h + off; off += S;
  _Float16* Bp = h + off;   off += (size_t)((wtot + 7) & ~7);
  int* tblBase = (int*)(h + off);
  size_t usedBytes = off * 2;
  bool prebuilt = (usedBytes + totTbl * 4 <= ws_size);

  // fused prep: feat + zero d_out + weight pack
  P.vox = F(0); P.vnp = I(1); P.f0 = f0;
  P.featTot = (N0 + 1) * 8; P.N0 = N0;
  P.dout = (float*)d_out; P.outTot = out_size;
  int prepTot = P.featTot + P.outTot + wtot;
  prep_all<<<cdiv_i(prepTot, 256), 256, 0, stream>>>(P, Bp, prepTot);

  const int l2rb[12] = {0, 0, 1, 2, 2, 3, 4, 4, 5, 6, 6, 7};
  const int* tblL[12];
  if (prebuilt) {
    hipMemsetAsync(tblBase, 0xFF, totTbl * 4, stream);
    rb_fill_all<<<cdiv_i(totFill, 256), 256, 0, stream>>>(RP, tblBase, totFill);
    for (int l = 0; l < 12; ++l) tblL[l] = tblBase + tblOff[l2rb[l]];
  } else {
    for (int l = 0; l < 12; ++l) tblL[l] = tblBase;
  }
  auto buildSeq = [&](int rb) {
    if (prebuilt) return;
    hipMemsetAsync(tblBase, 0xFF, tblInts[rb] * 4, stream);
    tbl_fill_kernel<<<cdiv_i(rbKs[rb] * rbRs[rb], 256), 256, 0, stream>>>(
        I(rbRin[rb]), I(rbRin[rb] + 1), tblBase, rbKs[rb], rbRs[rb], rbNout[rb]);
  };

#define CONV16(Kk, CIP, CO, KSv, CGv, CBv, IN, LI, OUTB, NOUT, NIN)           \
  do {                                                                        \
    constexpr int rowsPerBlk = (4 / (KSv * CGv)) * 16;                        \
    int nblk = cdiv_i(NOUT, rowsPerBlk) * CBv;                                \
    conv_mfma<Kk, CIP, CO, KSv, CGv, CBv><<<nblk, 256, 0, stream>>>(          \
        IN, Bp + bpOff[LI], tblL[LI], F(wIdx[LI] + 1), F(wIdx[LI] + 2),       \
        OUTB, NOUT, NIN);                                                     \
  } while (0)
#define CONV32(Kk, CIP, CO, KSv, CGv, CBv, IN, LI, OUTB, NOUT, NIN)           \
  do {                                                                        \
    constexpr int rowsPerBlk = (4 / (KSv * CGv)) * 32;                        \
    int nblk = cdiv_i(NOUT, rowsPerBlk) * CBv;                                \
    conv_mfma32<Kk, CIP, CO, KSv, CGv, CBv><<<nblk, 256, 0, stream>>>(        \
        IN, Bp + bpOff[LI], tblL[LI], F(wIdx[LI] + 1), F(wIdx[LI] + 2),       \
        OUTB, NOUT, NIN);                                                     \
  } while (0)

  // stage 1 (narrow -> 16x16 path)
  buildSeq(0);
  CONV16(27, 8, 16, 1, 1, 1, f0, 0, bufA, N0, N0);     // conv_in
  CONV16(27, 16, 16, 2, 1, 1, bufA, 1, bufB, N0, N0);  // conv1
  // stage 2
  buildSeq(1);
  CONV16(27, 16, 32, 2, 1, 1, bufB, 2, bufA, n2, N0);  // conv2a
  buildSeq(2);
  CONV32(27, 32, 32, 4, 1, 1, bufA, 3, bufB, n2, n2);  // conv2b
  CONV32(27, 32, 32, 4, 1, 1, bufB, 4, bufA, n2, n2);  // conv2c
  // stage 3
  buildSeq(3);
  CONV32(27, 32, 64, 4, 1, 1, bufA, 5, bufB, n3, n2);  // conv3a
  buildSeq(4);
  CONV32(27, 64, 64, 4, 1, 1, bufB, 6, bufA, n3, n3);  // conv3b
  CONV32(27, 64, 64, 4, 1, 1, bufA, 7, bufB, n3, n3);  // conv3c
  // stage 4
  buildSeq(5);
  CONV32(27, 64, 64, 4, 1, 1, bufB, 8, bufA, n4, n3);  // conv4a
  buildSeq(6);
  CONV32(27, 64, 64, 4, 1, 1, bufA, 9, bufB, n4, n4);  // conv4b
  CONV32(27, 64, 64, 4, 1, 1, bufB, 10, bufA, n4, n4); // conv4c
  // out conv (K=3, Co=128) -> 16x16 path
  buildSeq(7);
  CONV16(3, 64, 128, 2, 2, 2, bufA, 11, bufB, no, n4); // conv_out
  segmax2<<<cdiv_i(no, 128), 256, 0, stream>>>(bufB, I(22), no, (float*)d_out);
#undef CONV16
#undef CONV32
}

// Round 13
// 430.210 us; speedup vs baseline: 1.0137x; 1.0137x over previous
//
#include <hip/hip_runtime.h>
#include <cstddef>
#include <cstdint>

typedef _Float16 half8 __attribute__((ext_vector_type(8)));
typedef float floatx4 __attribute__((ext_vector_type(4)));
typedef float floatx16 __attribute__((ext_vector_type(16)));

static inline int cdiv_i(int a, int b) { return (a + b - 1) / b; }

// ---- fused rulebook inversion, TRANSPOSED tables: tbl[k*nout + o] = in
struct RB { const int* rin; const int* rout; int K, R, nout, start, end, off; };
struct RBs { RB d[8]; };
__global__ void rb_fill_all(RBs P, int* __restrict__ tbl, int total) {
  int idx = blockIdx.x * blockDim.x + threadIdx.x;
  if (idx >= total) return;
#pragma unroll
  for (int l = 0; l < 8; ++l) {
    if (idx >= P.d[l].start && idx < P.d[l].end) {
      const RB rb = P.d[l];
      int e = idx - rb.start;
      int o = rb.rout[e];
      if ((unsigned)o < (unsigned)rb.nout) {
        int k = e / rb.R;
        tbl[rb.off + (size_t)k * rb.nout + o] = rb.rin[e];
      }
    }
  }
}

__global__ void tbl_fill_kernel(const int* __restrict__ rin,
                                const int* __restrict__ rout,
                                int* __restrict__ tbl, int K, int R, int nout) {
  int e = blockIdx.x * blockDim.x + threadIdx.x;
  if (e >= K * R) return;
  int o = rout[e];
  if ((unsigned)o >= (unsigned)nout) return;
  int k = e / R;
  tbl[(size_t)k * nout + o] = rin[e];
}

// ---- fused prep: feat (f16 pad8) + zero d_out + weight pack
struct WP { const float* W; int K, Ci, CiPad, Co, start, end, off, p32; };
struct WPs {
  WP d[12];
  const float* vox; const int* vnp; _Float16* f0; int featTot, N0;
  float* dout; int outTot, wStart, wEnd;
};
__global__ void prep_all(WPs P, _Float16* __restrict__ Bp, int total) {
  int idx = blockIdx.x * blockDim.x + threadIdx.x;
  if (idx >= total) return;
  if (idx < P.featTot) {
    int i = idx >> 3, c = idx & 7;
    float v = 0.f;
    if (i < P.N0 && c < 4) {
      const float* p = P.vox + (size_t)i * 20 + c;
      v = (p[0] + p[4] + p[8] + p[12] + p[16]) / fmaxf((float)P.vnp[i], 1.f);
    }
    P.f0[idx] = (_Float16)v;
    return;
  }
  if (idx < P.featTot + P.outTot) {
    P.dout[idx - P.featTot] = 0.f;
    return;
  }
  int widx = idx - P.featTot - P.outTot;
#pragma unroll
  for (int l = 0; l < 12; ++l) {
    if (widx >= P.d[l].start && widx < P.d[l].end) {
      const WP w = P.d[l];
      int e = widx - w.start;
      int j = e & 7;
      int lane = (e >> 3) & 63;
      int rest = e >> 9;
      float v;
      if (w.p32) {
        int NT = w.Co >> 5;
        int t = rest % NT, ch = rest / NT;
        int SUB = w.CiPad >> 4;
        int ko = ch / SUB, s = ch % SUB;
        int ci = s * 16 + ((lane >> 5) << 3) + j;
        int col = t * 32 + (lane & 31);
        v = w.W[((size_t)ko * w.Ci + ci) * w.Co + col];
      } else {
        int NT = w.Co >> 4;
        int t = rest % NT, ch = rest / NT;
        int kk = ch * 32 + ((lane >> 4) << 3) + j;
        int k = kk / w.CiPad, ci = kk % w.CiPad;
        int n = t * 16 + (lane & 15);
        v = (k < w.K && ci < w.Ci) ? w.W[((size_t)k * w.Ci + ci) * w.Co + n] : 0.f;
      }
      Bp[w.off + e] = (_Float16)v;
    }
  }
}

// ======== 16x16x32 path ========
template <int K, int CiPad, int Co, int KS, int CG, int CBLK>
__global__ __launch_bounds__(256) void conv_mfma(
    const _Float16* __restrict__ feat, const _Float16* __restrict__ Bp,
    const int* __restrict__ tbl, const float* __restrict__ sc,
    const float* __restrict__ bi, _Float16* __restrict__ out,
    int nout, int nin) {
  constexpr int NT = Co / 16;
  constexpr int NTE = NT / CBLK;
  constexpr int NTW = NTE / CG;
  constexpr int RG = 4 / (KS * CG);
  static_assert(KS * CG * RG == 4 && RG >= 1 && NT % CBLK == 0 && NTE % CG == 0);
  constexpr int NCH = (K * CiPad + 31) / 32;
  constexpr int L2C = (CiPad == 8) ? 3 : 4;
  constexpr int DIV = (CiPad >= 32) ? (CiPad / 32) : 1;
  constexpr int CoP = NTE * 16 + 4;

  __shared__ float red[(KS > 1) ? (KS - 1) * RG * 16 * CoP : 1];

  if (blockIdx.x == 0 && threadIdx.x < Co)
    out[(size_t)nout * Co + threadIdx.x] = (_Float16)0.f;

  int id = blockIdx.x;
  { int nb = gridDim.x, nb8 = (nb >> 3) << 3;
    if (id < nb8) { int per = nb >> 3; id = (id & 7) * per + (id >> 3); } }
  const int rt = id / CBLK, cb = id % CBLK;
  const int wave = threadIdx.x >> 6, lane = threadIdx.x & 63;
  const int ks = wave % KS;
  const int cg = (wave / KS) % CG;
  const int rowg = wave / (KS * CG);
  const int m = lane & 15, lb = (lane >> 4) * 8;
  const int i0 = (rt * RG + rowg) * 16;
  if constexpr (KS == 1) { if (i0 >= nout) return; }
  const int row = i0 + m;
  const bool rOK = row < nout;
  const int ct0 = cb * NTE + cg * NTW;

  floatx4 acc[NTW];
#pragma unroll
  for (int n = 0; n < NTW; ++n) { floatx4 z = {0,0,0,0}; acc[n] = z; }

  if constexpr (CiPad >= 32) {
    constexpr int NKW = (K + KS - 1) / KS;
    constexpr int NC = NKW * DIV;
    constexpr int DA = NC < 8 ? NC : 8;
    constexpr int DB = NC < 2 ? NC : 2;
    int idx[NKW];
#pragma unroll
    for (int q = 0; q < NKW; ++q) {
      int k = ks * NKW + q;
      int jj = (rOK && k < K) ? tbl[(size_t)k * nout + row] : -1;
      idx[q] = (jj < 0) ? nin : jj;
    }
    half8 ap[DA]; half8 bq[DB][NTW];
#pragma unroll
    for (int d = 0; d < DA; ++d)
      ap[d] = *(const half8*)(feat + (size_t)idx[d / DIV] * CiPad + (d % DIV) * 32 + lb);
#pragma unroll
    for (int d = 0; d < DB; ++d) {
      int k = ks * NKW + d / DIV;
      int ch = ((k < K) ? k : (K - 1)) * DIV + (d % DIV);
#pragma unroll
      for (int n = 0; n < NTW; ++n)
        bq[d][n] = *(const half8*)(Bp + ((size_t)ch * NT * 64 + lane) * 8 +
                                   (size_t)(ct0 + n) * 512);
    }
#pragma unroll
    for (int ii = 0; ii < NC; ++ii) {
      half8 a = ap[ii % DA];
      half8 bt[NTW];
#pragma unroll
      for (int n = 0; n < NTW; ++n) bt[n] = bq[ii % DB][n];
      if (ii + DA < NC) {
        int nx = ii + DA;
        ap[ii % DA] = *(const half8*)(feat + (size_t)idx[nx / DIV] * CiPad +
                                      (nx % DIV) * 32 + lb);
      }
      if (ii + DB < NC) {
        int nx = ii + DB;
        int k = ks * NKW + nx / DIV;
        int ch = ((k < K) ? k : (K - 1)) * DIV + (nx % DIV);
#pragma unroll
        for (int n = 0; n < NTW; ++n)
          bq[ii % DB][n] = *(const half8*)(Bp + ((size_t)ch * NT * 64 + lane) * 8 +
                                           (size_t)(ct0 + n) * 512);
      }
#pragma unroll
      for (int n = 0; n < NTW; ++n)
        acc[n] = __builtin_amdgcn_mfma_f32_16x16x32_f16(a, bt[n], acc[n], 0, 0, 0);
    }
  } else {
    constexpr int NCW = (NCH + KS - 1) / KS;
    constexpr int DA = NCW < 8 ? NCW : 8;
    constexpr int DB = NCW < 2 ? NCW : 2;
    int idx[NCW];
#pragma unroll
    for (int q = 0; q < NCW; ++q) {
      int ch = ks * NCW + q;
      int ko = (ch * 32 + lb) >> L2C;
      int jj = (rOK && ko < K && ch < NCH) ? tbl[(size_t)ko * nout + row] : -1;
      idx[q] = (jj < 0) ? nin : jj;
    }
    half8 ap[DA]; half8 bq[DB][NTW];
#pragma unroll
    for (int d = 0; d < DA; ++d) {
      int ch = ks * NCW + d;
      ap[d] = *(const half8*)(feat + (size_t)idx[d] * CiPad + ((ch * 32 + lb) & (CiPad - 1)));
    }
#pragma unroll
    for (int d = 0; d < DB; ++d) {
      int ch = ks * NCW + d;
      if (ch >= NCH) ch = NCH - 1;
#pragma unroll
      for (int n = 0; n < NTW; ++n)
        bq[d][n] = *(const half8*)(Bp + ((size_t)ch * NT * 64 + lane) * 8 +
                                   (size_t)(ct0 + n) * 512);
    }
#pragma unroll
    for (int ii = 0; ii < NCW; ++ii) {
      half8 a = ap[ii % DA];
      half8 bt[NTW];
#pragma unroll
      for (int n = 0; n < NTW; ++n) bt[n] = bq[ii % DB][n];
      if (ii + DA < NCW) {
        int nx = ii + DA;
        int ch = ks * NCW + nx;
        ap[ii % DA] = *(const half8*)(feat + (size_t)idx[nx] * CiPad +
                                      ((ch * 32 + lb) & (CiPad - 1)));
      }
      if (ii + DB < NCW) {
        int nx = ii + DB;
        int ch = ks * NCW + nx;
        if (ch >= NCH) ch = NCH - 1;
#pragma unroll
        for (int n = 0; n < NTW; ++n)
          bq[ii % DB][n] = *(const half8*)(Bp + ((size_t)ch * NT * 64 + lane) * 8 +
                                           (size_t)(ct0 + n) * 512);
      }
#pragma unroll
      for (int n = 0; n < NTW; ++n)
        acc[n] = __builtin_amdgcn_mfma_f32_16x16x32_f16(a, bt[n], acc[n], 0, 0, 0);
    }
  }

  const int rl = (lane >> 4) * 4;
  if constexpr (KS > 1) {
    if (ks > 0) {
#pragma unroll
      for (int n = 0; n < NTW; ++n) {
        int lcol = (cg * NTW + n) * 16 + m;
#pragma unroll
        for (int r = 0; r < 4; ++r)
          red[((ks - 1) * RG + rowg) * 16 * CoP + (rl + r) * CoP + lcol] = acc[n][r];
      }
    }
    __syncthreads();
    if (ks > 0) return;
#pragma unroll
    for (int s = 1; s < KS; ++s)
#pragma unroll
      for (int n = 0; n < NTW; ++n) {
        int lcol = (cg * NTW + n) * 16 + m;
#pragma unroll
        for (int r = 0; r < 4; ++r)
          acc[n][r] += red[((s - 1) * RG + rowg) * 16 * CoP + (rl + r) * CoP + lcol];
      }
  }

#pragma unroll
  for (int n = 0; n < NTW; ++n) {
    int col = (ct0 + n) * 16 + m;
    float s_ = sc[col], b_ = bi[col];
#pragma unroll
    for (int r = 0; r < 4; ++r) {
      int orow = i0 + rl + r;
      if (orow < nout)
        out[(size_t)orow * Co + col] = (_Float16)fmaxf(fmaf(acc[n][r], s_, b_), 0.f);
    }
  }
}

// ======== 32x32x16 path (Ci>=32 heavy layers), contiguous-k per wave ========
template <int K, int CiPad, int Co, int KS, int CG, int CBLK>
__global__ __launch_bounds__(256) void conv_mfma32(
    const _Float16* __restrict__ feat, const _Float16* __restrict__ Bp,
    const int* __restrict__ tbl, const float* __restrict__ sc,
    const float* __restrict__ bi, _Float16* __restrict__ out,
    int nout, int nin) {
  constexpr int NT = Co / 32;
  constexpr int NTE = NT / CBLK;
  constexpr int NTW = NTE / CG;
  constexpr int RG = 4 / (KS * CG);
  static_assert(KS * CG * RG == 4 && RG >= 1 && NT % CBLK == 0 && NTE % CG == 0 && NTW >= 1);
  constexpr int SUB = CiPad / 16;
  constexpr int NKW = (K + KS - 1) / KS;
  constexpr int NC = NKW * SUB;
  constexpr int DA = NC < 8 ? NC : 8;
  constexpr int DB = NC < 2 ? NC : 2;
  constexpr int CoP = NTE * 32 + 4;

  __shared__ float red[(KS > 1) ? (KS - 1) * RG * 32 * CoP : 1];

  if (blockIdx.x == 0 && threadIdx.x < Co)
    out[(size_t)nout * Co + threadIdx.x] = (_Float16)0.f;

  int id = blockIdx.x;
  { int nb = gridDim.x, nb8 = (nb >> 3) << 3;
    if (id < nb8) { int per = nb >> 3; id = (id & 7) * per + (id >> 3); } }
  const int rt = id / CBLK, cb = id % CBLK;
  const int wave = threadIdx.x >> 6, lane = threadIdx.x & 63;
  const int ks = wave % KS;
  const int cg = (wave / KS) % CG;
  const int rowg = wave / (KS * CG);
  const int m = lane & 31, lb = (lane >> 5) * 8, h = lane >> 5;
  const int i0 = (rt * RG + rowg) * 32;
  if constexpr (KS == 1) { if (i0 >= nout) return; }
  const int row = i0 + m;
  const bool rOK = row < nout;
  const int ct0 = cb * NTE + cg * NTW;

  floatx16 acc[NTW];
#pragma unroll
  for (int n = 0; n < NTW; ++n)
#pragma unroll
    for (int r = 0; r < 16; ++r) acc[n][r] = 0.f;

  int idx[NKW];
#pragma unroll
  for (int q = 0; q < NKW; ++q) {
    int k = ks * NKW + q;
    int jj = (rOK && k < K) ? tbl[(size_t)k * nout + row] : -1;
    idx[q] = (jj < 0) ? nin : jj;
  }

  half8 ap[DA]; half8 bq[DB][NTW];
#pragma unroll
  for (int d = 0; d < DA; ++d)
    ap[d] = *(const half8*)(feat + (size_t)idx[d / SUB] * CiPad + (d % SUB) * 16 + lb);
#pragma unroll
  for (int d = 0; d < DB; ++d) {
    int k = ks * NKW + d / SUB;
    int ch = ((k < K) ? k : (K - 1)) * SUB + (d % SUB);
#pragma unroll
    for (int n = 0; n < NTW; ++n)
      bq[d][n] = *(const half8*)(Bp + (size_t)(ch * NT + ct0 + n) * 512 + lane * 8);
  }
#pragma unroll
  for (int ii = 0; ii < NC; ++ii) {
    half8 a = ap[ii % DA];
    half8 bt[NTW];
#pragma unroll
    for (int n = 0; n < NTW; ++n) bt[n] = bq[ii % DB][n];
    if (ii + DA < NC) {
      int nx = ii + DA;
      ap[ii % DA] = *(const half8*)(feat + (size_t)idx[nx / SUB] * CiPad +
                                    (nx % SUB) * 16 + lb);
    }
    if (ii + DB < NC) {
      int nx = ii + DB;
      int k = ks * NKW + nx / SUB;
      int ch = ((k < K) ? k : (K - 1)) * SUB + (nx % SUB);
#pragma unroll
      for (int n = 0; n < NTW; ++n)
        bq[ii % DB][n] = *(const half8*)(Bp + (size_t)(ch * NT + ct0 + n) * 512 + lane * 8);
    }
#pragma unroll
    for (int n = 0; n < NTW; ++n)
      acc[n] = __builtin_amdgcn_mfma_f32_32x32x16_f16(a, bt[n], acc[n], 0, 0, 0);
  }

  if constexpr (KS > 1) {
    if (ks > 0) {
#pragma unroll
      for (int n = 0; n < NTW; ++n) {
        int lcol = (cg * NTW + n) * 32 + m;
#pragma unroll
        for (int reg = 0; reg < 16; ++reg) {
          int r = (reg & 3) + 8 * (reg >> 2) + 4 * h;
          red[((ks - 1) * RG + rowg) * 32 * CoP + r * CoP + lcol] = acc[n][reg];
        }
      }
    }
    __syncthreads();
    if (ks > 0) return;
#pragma unroll
    for (int s = 1; s < KS; ++s)
#pragma unroll
      for (int n = 0; n < NTW; ++n) {
        int lcol = (cg * NTW + n) * 32 + m;
#pragma unroll
        for (int reg = 0; reg < 16; ++reg) {
          int r = (reg & 3) + 8 * (reg >> 2) + 4 * h;
          acc[n][reg] += red[((s - 1) * RG + rowg) * 32 * CoP + r * CoP + lcol];
        }
      }
  }

#pragma unroll
  for (int n = 0; n < NTW; ++n) {
    int col = (ct0 + n) * 32 + m;
    float s_ = sc[col], b_ = bi[col];
#pragma unroll
    for (int reg = 0; reg < 16; ++reg) {
      int orow = i0 + (reg & 3) + 8 * (reg >> 2) + 4 * h;
      if (orow < nout)
        out[(size_t)orow * Co + col] = (_Float16)fmaxf(fmaf(acc[n][reg], s_, b_), 0.f);
    }
  }
}

// ---- two-stage segment max; batch_out nondecreasing; one atomic per run.
__global__ __launch_bounds__(256) void segmax2(const _Float16* __restrict__ x,
                                               const int* __restrict__ batch,
                                               int n, float* __restrict__ out) {
  const int RPB = 128;
  int c = threadIdx.x & 127, g = threadIdx.x >> 7;
  int r0 = blockIdx.x * RPB + g;
  int rend = min(n, blockIdx.x * RPB + RPB);
  float mx = 0.f;
  int cb = -1;
  for (int r = r0; r < rend; r += 2) {
    int b = batch[r];
    if (b != cb) {
      if (cb >= 0) atomicMax((int*)out + ((size_t)cb << 7) + c, __float_as_int(mx));
      cb = b; mx = 0.f;
    }
    mx = fmaxf(mx, (float)x[(size_t)r * 128 + c]);
  }
  if (cb >= 0) atomicMax((int*)out + ((size_t)cb << 7) + c, __float_as_int(mx));
}

extern "C" void kernel_launch(void* const* d_in, const int* in_sizes, int n_in,
                              void* d_out, int out_size, void* d_ws, size_t ws_size,
                              hipStream_t stream) {
  auto I = [&](int idx) { return (const int*)d_in[idx]; };
  auto F = [&](int idx) { return (const float*)d_in[idx]; };

  const int N0  = in_sizes[1];
  const int R1  = in_sizes[3] / 27;
  const int R2s = in_sizes[5] / 27;
  const int n2  = in_sizes[7];
  const int R2  = in_sizes[8] / 27;
  const int R3s = in_sizes[10] / 27;
  const int n3  = in_sizes[12];
  const int R3  = in_sizes[13] / 27;
  const int R4s = in_sizes[15] / 27;
  const int n4  = in_sizes[17];
  const int R4  = in_sizes[18] / 27;
  const int Ro  = in_sizes[20] / 3;
  const int no  = in_sizes[22];

  const int wIdx[12] = {23, 26, 29, 32, 35, 38, 41, 44, 47, 50, 53, 56};
  const int Ks[12]   = {27, 27, 27, 27, 27, 27, 27, 27, 27, 27, 27, 3};
  const int Cis[12]  = {4, 16, 16, 32, 32, 32, 64, 64, 64, 64, 64, 64};
  const int Cos[12]  = {16, 16, 32, 32, 32, 64, 64, 64, 64, 64, 64, 128};
  const int P32[12]  = {0, 0, 0, 1, 1, 1, 1, 1, 1, 1, 1, 0};
  WPs P;
  int wtot = 0;
  int bpOff[12];
  for (int l = 0; l < 12; ++l) {
    int cip = Cis[l] < 8 ? 8 : Cis[l];
    int sz;
    if (P32[l]) sz = Ks[l] * (cip / 16) * (Cos[l] / 32) * 512;
    else        sz = ((Ks[l] * cip + 31) / 32) * (Cos[l] / 16) * 512;
    P.d[l].W = F(wIdx[l]);
    P.d[l].K = Ks[l]; P.d[l].Ci = Cis[l]; P.d[l].CiPad = cip; P.d[l].Co = Cos[l];
    P.d[l].start = wtot; P.d[l].end = wtot + sz; P.d[l].off = wtot; P.d[l].p32 = P32[l];
    bpOff[l] = wtot;
    wtot += sz;
  }

  RBs RP;
  const int rbRin[8]  = {3, 5, 8, 10, 13, 15, 18, 20};
  const int rbRs[8]   = {R1, R2s, R2, R3s, R3, R4s, R4, Ro};
  const int rbKs[8]   = {27, 27, 27, 27, 27, 27, 27, 3};
  const int rbNout[8] = {N0, n2, n2, n3, n3, n4, n4, no};
  size_t tblInts[8], tblOff[8];
  size_t totTbl = 0;
  int totFill = 0;
  for (int l = 0; l < 8; ++l) {
    tblInts[l] = (size_t)rbNout[l] * rbKs[l];
    tblOff[l] = totTbl;
    totTbl += tblInts[l];
    RP.d[l].rin = I(rbRin[l]);
    RP.d[l].rout = I(rbRin[l] + 1);
    RP.d[l].K = rbKs[l]; RP.d[l].R = rbRs[l]; RP.d[l].nout = rbNout[l];
    RP.d[l].start = totFill;
    totFill += rbKs[l] * rbRs[l];
    RP.d[l].end = totFill;
    RP.d[l].off = (int)tblOff[l];
  }

  size_t S = (size_t)(N0 + 1) * 16;
  auto smax = [&](size_t v) { if (v > S) S = v; };
  smax((size_t)(n2 + 1) * 32);
  smax((size_t)(n3 + 1) * 64);
  smax((size_t)(n4 + 1) * 64);
  smax((size_t)(no + 1) * 128);
  S = (S + 7) & ~(size_t)7;

  _Float16* h = (_Float16*)d_ws;
  size_t off = 0;
  _Float16* f0 = h + off;   off += (size_t)(N0 + 1) * 8;
  _Float16* bufA = h + off; off += S;
  _Float16* bufB = h + off; off += S;
  _Float16* Bp = h + off;   off += (size_t)((wtot + 7) & ~7);
  int* tblBase = (int*)(h + off);
  size_t usedBytes = off * 2;
  bool prebuilt = (usedBytes + totTbl * 4 <= ws_size);

  // fused prep: feat + zero d_out + weight pack
  P.vox = F(0); P.vnp = I(1); P.f0 = f0;
  P.featTot = (N0 + 1) * 8; P.N0 = N0;
  P.dout = (float*)d_out; P.outTot = out_size;
  int prepTot = P.featTot + P.outTot + wtot;
  prep_all<<<cdiv_i(prepTot, 256), 256, 0, stream>>>(P, Bp, prepTot);

  const int l2rb[12] = {0, 0, 1, 2, 2, 3, 4, 4, 5, 6, 6, 7};
  const int* tblL[12];
  if (prebuilt) {
    hipMemsetAsync(tblBase, 0xFF, totTbl * 4, stream);
    rb_fill_all<<<cdiv_i(totFill, 256), 256, 0, stream>>>(RP, tblBase, totFill);
    for (int l = 0; l < 12; ++l) tblL[l] = tblBase + tblOff[l2rb[l]];
  } else {
    for (int l = 0; l < 12; ++l) tblL[l] = tblBase;
  }
  auto buildSeq = [&](int rb) {
    if (prebuilt) return;
    hipMemsetAsync(tblBase, 0xFF, tblInts[rb] * 4, stream);
    tbl_fill_kernel<<<cdiv_i(rbKs[rb] * rbRs[rb], 256), 256, 0, stream>>>(
        I(rbRin[rb]), I(rbRin[rb] + 1), tblBase, rbKs[rb], rbRs[rb], rbNout[rb]);
  };

#define CONV16(Kk, CIP, CO, KSv, CGv, CBv, IN, LI, OUTB, NOUT, NIN)           \
  do {                                                                        \
    constexpr int rowsPerBlk = (4 / (KSv * CGv)) * 16;                        \
    int nblk = cdiv_i(NOUT, rowsPerBlk) * CBv;                                \
    conv_mfma<Kk, CIP, CO, KSv, CGv, CBv><<<nblk, 256, 0, stream>>>(          \
        IN, Bp + bpOff[LI], tblL[LI], F(wIdx[LI] + 1), F(wIdx[LI] + 2),       \
        OUTB, NOUT, NIN);                                                     \
  } while (0)
#define CONV32(Kk, CIP, CO, KSv, CGv, CBv, IN, LI, OUTB, NOUT, NIN)           \
  do {                                                                        \
    constexpr int rowsPerBlk = (4 / (KSv * CGv)) * 32;                        \
    int nblk = cdiv_i(NOUT, rowsPerBlk) * CBv;                                \
    conv_mfma32<Kk, CIP, CO, KSv, CGv, CBv><<<nblk, 256, 0, stream>>>(        \
        IN, Bp + bpOff[LI], tblL[LI], F(wIdx[LI] + 1), F(wIdx[LI] + 2),       \
        OUTB, NOUT, NIN);                                                     \
  } while (0)

  // stage 1 (narrow -> 16x16 path)
  buildSeq(0);
  CONV16(27, 8, 16, 1, 1, 1, f0, 0, bufA, N0, N0);     // conv_in
  CONV16(27, 16, 16, 2, 1, 1, bufA, 1, bufB, N0, N0);  // conv1
  // stage 2
  buildSeq(1);
  CONV16(27, 16, 32, 2, 1, 1, bufB, 2, bufA, n2, N0);  // conv2a
  buildSeq(2);
  CONV32(27, 32, 32, 4, 1, 1, bufA, 3, bufB, n2, n2);  // conv2b
  CONV32(27, 32, 32, 4, 1, 1, bufB, 4, bufA, n2, n2);  // conv2c
  // stage 3
  buildSeq(3);
  CONV32(27, 32, 64, 4, 1, 1, bufA, 5, bufB, n3, n2);  // conv3a
  buildSeq(4);
  CONV32(27, 64, 64, 4, 1, 1, bufB, 6, bufA, n3, n3);  // conv3b
  CONV32(27, 64, 64, 4, 1, 1, bufA, 7, bufB, n3, n3);  // conv3c
  // stage 4
  buildSeq(5);
  CONV32(27, 64, 64, 4, 1, 1, bufB, 8, bufA, n4, n3);  // conv4a
  buildSeq(6);
  CONV32(27, 64, 64, 4, 1, 1, bufA, 9, bufB, n4, n4);  // conv4b
  CONV32(27, 64, 64, 4, 1, 1, bufB, 10, bufA, n4, n4); // conv4c
  // out conv (K=3, Co=128) -> 16x16 path
  buildSeq(7);
  CONV16(3, 64, 128, 2, 2, 2, bufA, 11, bufB, no, n4); // conv_out
  segmax2<<<cdiv_i(no, 128), 256, 0, stream>>>(bufB, I(22), no, (float*)d_out);
#undef CONV16
#undef CONV32
}